// Round 14
// baseline (5530.588 us; speedup 1.0000x reference)
//
#include <hip/hip_runtime.h>

// RNN + FC readout on MI355X — f32 recurrence, quarter-split, quad-parallel finalize,
// tagged single-RTT exchange with paced spins, 1 lgkm-barrier/step.
//   A: xp[B,T,H] = input @ w_ih^T + b_h   (f32 GEMM; cols 0..255 -> d_out, 256..511 -> d_ws)
//   B: h_t = tanh(xp_t + h_{t-1} @ w_hh^T): 256 blocks = 4/batch. Lane t: row q*128+(t>>2),
//      k-quarter t&3 (32 float4 W regs). Intra-quad DPP reduce (quad_perm, R5-proven) ->
//      every quad leader finalizes+publishes its row right after FMA (parallel across all
//      8 waves; publish ~400cy earlier than R13). Probes paced with s_sleep(1).
//   C: out[B,T,O] = h @ w_out^T + b_out   (f16-dot2 GEMM, f32 in-place over d_out)
//
// Refuted: f16 W/h (R7), 2-batch interleave (R10), early-race probes (R13), row_ror DPP
// (R8). Proven: tagged u64 exchange (R11), lgkm-only barriers (R12), quad_perm DPP (R5).

typedef _Float16 f16;
typedef __attribute__((ext_vector_type(2))) _Float16 half2_t;
typedef __attribute__((ext_vector_type(4))) float float4_t;

#define NIN    256
#define NHID   512
#define NOUT   256
#define NBATCH 64
#define NT     2048

#define FL4(p) (*reinterpret_cast<const float4_t*>(p))
#define LOADA(p)     __hip_atomic_load((p), __ATOMIC_RELAXED, __HIP_MEMORY_SCOPE_AGENT)
#define STOREA(p, v) __hip_atomic_store((p), (v), __ATOMIC_RELAXED, __HIP_MEMORY_SCOPE_AGENT)

// LDS-only barrier (R12-proven): orders ds ops without draining vmcnt.
#define LDS_BAR() do {                                              \
    asm volatile("s_waitcnt lgkmcnt(0)\n\ts_barrier" ::: "memory"); \
    __builtin_amdgcn_sched_barrier(0);                              \
  } while (0)

#if __has_builtin(__builtin_amdgcn_fdot2)
__device__ __forceinline__ float fdot2f(half2_t a, half2_t b, float c) {
  return __builtin_amdgcn_fdot2(a, b, c, false);   // v_dot2_f32_f16 (phase C only)
}
#else
__device__ __forceinline__ float fdot2f(half2_t a, half2_t b, float c) {
  return c + (float)a.x * (float)b.x + (float)a.y * (float)b.y;
}
#endif

__device__ __forceinline__ float tanh_fast(float x) {   // R5/R12-proven
  float e = __expf(2.0f * x);
  return 1.0f - 2.0f / (e + 1.0f);
}

__device__ unsigned long long g_pub[NBATCH][2][NHID];   // (tag s+1)<<32 | f32 bits; 512 KB

__global__ __launch_bounds__(256) void k_zero() {
  ((unsigned long long*)g_pub)[blockIdx.x * 256 + threadIdx.x] = 0ull;   // grid 256
}

// ---------------- Phase A: in-projection GEMM, full f32 (proven R5..R13) ----------------
__global__ __launch_bounds__(256) void k_inproj(
    const float* __restrict__ x, const float* __restrict__ w,
    const float* __restrict__ bias, float* __restrict__ xplo, float* __restrict__ xphi)
{
  __shared__ float xs[32][260];
  __shared__ float wsT[8][520];
  const int t = threadIdx.x;
  const int m0 = blockIdx.x * 32;
  const int mthr = t & 3;
  const int nthr = t >> 2;

  #pragma unroll
  for (int r = 0; r < 8; ++r) {
    int f = (t + 256 * r) * 4;
    int row = f >> 8, col = f & 255;
    *(float4_t*)&xs[row][col] =
        *reinterpret_cast<const float4_t*>(x + (size_t)(m0 + row) * NIN + col);
  }

  float acc[8][8];
  #pragma unroll
  for (int nn = 0; nn < 8; ++nn) {
    float bv = bias[nthr * 8 + nn];
    #pragma unroll
    for (int mm = 0; mm < 8; ++mm) acc[nn][mm] = bv;
  }

  for (int kc = 0; kc < 32; ++kc) {
    __syncthreads();
    #pragma unroll
    for (int r = 0; r < 4; ++r) {
      int f = (t + 256 * r) * 4;
      int n = f >> 3, k0 = f & 7;
      float4_t v = *reinterpret_cast<const float4_t*>(w + (size_t)n * NIN + kc * 8 + k0);
      #pragma unroll
      for (int j = 0; j < 4; ++j) wsT[k0 + j][n] = v[j];
    }
    __syncthreads();
    #pragma unroll
    for (int kp = 0; kp < 8; ++kp) {
      float4_t wv0 = *(const float4_t*)&wsT[kp][nthr * 8];
      float4_t wv1 = *(const float4_t*)&wsT[kp][nthr * 8 + 4];
      #pragma unroll
      for (int mm = 0; mm < 8; ++mm) {
        float xv = xs[mthr * 8 + mm][kc * 8 + kp];
        acc[0][mm] = fmaf(wv0.x, xv, acc[0][mm]);
        acc[1][mm] = fmaf(wv0.y, xv, acc[1][mm]);
        acc[2][mm] = fmaf(wv0.z, xv, acc[2][mm]);
        acc[3][mm] = fmaf(wv0.w, xv, acc[3][mm]);
        acc[4][mm] = fmaf(wv1.x, xv, acc[4][mm]);
        acc[5][mm] = fmaf(wv1.y, xv, acc[5][mm]);
        acc[6][mm] = fmaf(wv1.z, xv, acc[6][mm]);
        acc[7][mm] = fmaf(wv1.w, xv, acc[7][mm]);
      }
    }
  }

  const int n0 = nthr * 8;
  float* dst = (n0 < 256) ? (xplo + n0) : (xphi + (n0 - 256));
  #pragma unroll
  for (int mm = 0; mm < 8; ++mm) {
    int m = m0 + mthr * 8 + mm;
    float4_t o0 = {acc[0][mm], acc[1][mm], acc[2][mm], acc[3][mm]};
    float4_t o1 = {acc[4][mm], acc[5][mm], acc[6][mm], acc[7][mm]};
    *reinterpret_cast<float4_t*>(dst + (size_t)m * 256)     = o0;
    *reinterpret_cast<float4_t*>(dst + (size_t)m * 256 + 4) = o1;
  }
}

// ---------------- Phase B: f32 recurrence, quad-parallel finalize ----------------
// block g: batch b=(g>>5)*8+(g&7), quarter q=(g>>3)&3 owns rows [q*128,+128).
// lane t: row r=q*128+(t>>2), k-quarter kq=t&3 -> W[r][kq*128..+128) in 32 float4 regs.
// Quad lanes hold the same row, 4 k-quarters; DPP quad reduce -> leader (kq==0) finalizes.
// Probe: thread t fetches row kq*128+(t>>2) (skipped when kq==q), paced by s_sleep.
// hl padded [4][132] so the 4 per-quad ds_read_b128 address groups are conflict-free.
__global__ __launch_bounds__(512, 1) void k_recur(
    const float* __restrict__ whh, float* outbuf, float* wsbuf)
{
  __shared__ __align__(16) float hl[2][4][132];     // [parity][k-quarter][128+4 pad]
  const int g = blockIdx.x;
  const int b = (g >> 5) * 8 + (g & 7);
  const int q = (g >> 3) & 3;
  const int t = threadIdx.x;
  const int kq = t & 3;
  const int ri = t >> 2;
  const int r  = q * 128 + ri;
  const bool lead = (kq == 0);
  const bool prb  = (kq != q);

  float4_t w[32];
  #pragma unroll
  for (int i = 0; i < 32; ++i)
    w[i] = FL4(whh + (size_t)r * NHID + kq * 128 + i * 4);

  float* xp = nullptr;
  float xq0 = 0.f, xq1 = 0.f;
  if (lead) {
    xp = ((q < 2) ? (outbuf + r) : (wsbuf + (r - 256))) + (size_t)b * NT * 256;
    xq0 = xp[0]; xq1 = xp[256];
  }

  hl[0][t >> 7][t & 127] = 0.0f;                    // h_{-1} = 0 (pads never read)
  __syncthreads();                                  // prologue: full drain once

  for (int s = 0; s < NT; ++s) {
    const int par = s & 1;

    // FMA over own k-quarter of h(s-1); 4 distinct bcast addresses, pad -> conflict-free
    const float4_t* h4 = (const float4_t*)&hl[par][kq][0];
    float4_t a = {0.f,0.f,0.f,0.f}, c = {0.f,0.f,0.f,0.f};
    #pragma unroll
    for (int i = 0; i < 32; i += 2) { a += w[i] * h4[i]; c += w[i + 1] * h4[i + 1]; }
    float4_t sv = a + c;
    float sum = (sv.x + sv.y) + (sv.z + sv.w);
    int xi;                                         // intra-quad reduce (R5-proven perms)
    xi = __builtin_amdgcn_update_dpp(0, __builtin_bit_cast(int, sum), 0xB1, 0xF, 0xF, true);
    sum += __builtin_bit_cast(float, xi);
    xi = __builtin_amdgcn_update_dpp(0, __builtin_bit_cast(int, sum), 0x4E, 0xF, 0xF, true);
    sum += __builtin_bit_cast(float, xi);

    if (lead) {                                     // finalize own row, publish ASAP
      float h = tanh_fast(sum + xq0);
      STOREA(&g_pub[b][par][r],
             ((unsigned long long)(unsigned)(s + 1) << 32) |
             (unsigned long long)__builtin_bit_cast(unsigned, h));
      hl[par ^ 1][q][ri] = h;
      xp[(size_t)s * 256] = h;                      // hs for phase C (fire-and-forget)
      xq0 = xq1;
      if (s + 2 < NT) xq1 = xp[(size_t)(s + 2) * 256];   // 2-step HBM prefetch
    }
    if (prb && s + 1 < NT) {                        // fetch peer h(s) row for next step
      unsigned long long pv = LOADA(&g_pub[b][par][kq * 128 + ri]);
      while ((unsigned)(pv >> 32) < (unsigned)(s + 1)) {
        __builtin_amdgcn_s_sleep(1);                // pace: cut LLC contention
        pv = LOADA(&g_pub[b][par][kq * 128 + ri]);
      }
      hl[par ^ 1][kq][ri] = __builtin_bit_cast(float, (unsigned)pv);
    }
    LDS_BAR();                                      // hl[par^1] complete (the only barrier)
  }
}

// ---------------- Phase C: out-projection (f16 dot2, f32 out, in-place; proven) ------------
__global__ __launch_bounds__(256) void k_outproj(
    const float* hlo, const float* hhi, const float* __restrict__ w,
    const float* __restrict__ bias, float* out)
{
  __shared__ half2_t xs[32][258];
  __shared__ half2_t ws[256][19];
  const int t = threadIdx.x;
  const int m0 = blockIdx.x * 32;
  const int nthr = t >> 2;
  const int mthr = t & 3;

  #pragma unroll
  for (int r = 0; r < 16; ++r) {
    int f = (t + 256 * r) * 4;
    int row = f >> 9, col = f & 511;
    const float* src = (col < 256) ? (hlo + (size_t)(m0 + row) * 256 + col)
                                   : (hhi + (size_t)(m0 + row) * 256 + (col - 256));
    float4_t v = *reinterpret_cast<const float4_t*>(src);
    xs[row][(col >> 1)]     = half2_t{(f16)v.x, (f16)v.y};
    xs[row][(col >> 1) + 1] = half2_t{(f16)v.z, (f16)v.w};
  }

  float acc[4][8];
  #pragma unroll
  for (int nn = 0; nn < 4; ++nn) {
    float bv = bias[nthr * 4 + nn];
    #pragma unroll
    for (int mm = 0; mm < 8; ++mm) acc[nn][mm] = bv;
  }

  for (int kc = 0; kc < 16; ++kc) {
    __syncthreads();
    #pragma unroll
    for (int r = 0; r < 8; ++r) {
      int f = (t + 256 * r) * 4;
      int row = f >> 5, col = f & 31;
      float4_t v = *reinterpret_cast<const float4_t*>(w + (size_t)row * NHID + kc * 32 + col);
      ws[row][(col >> 1)]     = half2_t{(f16)v.x, (f16)v.y};
      ws[row][(col >> 1) + 1] = half2_t{(f16)v.z, (f16)v.w};
    }
    __syncthreads();
    #pragma unroll
    for (int kp = 0; kp < 16; ++kp) {
      half2_t wv[4], xv[8];
      #pragma unroll
      for (int nn = 0; nn < 4; ++nn) wv[nn] = ws[nthr * 4 + nn][kp];
      #pragma unroll
      for (int mm = 0; mm < 8; ++mm) xv[mm] = xs[mthr * 8 + mm][kc * 16 + kp];
      #pragma unroll
      for (int nn = 0; nn < 4; ++nn)
        #pragma unroll
        for (int mm = 0; mm < 8; ++mm)
          acc[nn][mm] = fdot2f(wv[nn], xv[mm], acc[nn][mm]);
    }
  }

  #pragma unroll
  for (int mm = 0; mm < 8; ++mm) {
    int m = m0 + mthr * 8 + mm;
    float4_t o = {acc[0][mm], acc[1][mm], acc[2][mm], acc[3][mm]};
    *reinterpret_cast<float4_t*>(out + (size_t)m * NOUT + nthr * 4) = o;
  }
}

extern "C" void kernel_launch(void* const* d_in, const int* in_sizes, int n_in,
                              void* d_out, int out_size, void* d_ws, size_t ws_size,
                              hipStream_t stream) {
  (void)in_sizes; (void)n_in; (void)ws_size; (void)out_size;
  const float* x     = (const float*)d_in[0];
  const float* w_ih  = (const float*)d_in[1];
  const float* w_hh  = (const float*)d_in[2];
  const float* b_h   = (const float*)d_in[3];
  const float* w_out = (const float*)d_in[4];
  const float* b_out = (const float*)d_in[5];

  float* outb = (float*)d_out;   // xp cols 0..255  -> h rows 0..255  -> y   (134 MB)
  float* wsb  = (float*)d_ws;    // xp cols 256..511 -> h rows 256..511     (134 MB, proven)

  k_zero   <<<256, 256, 0, stream>>>();
  k_inproj <<<(NBATCH * NT) / 32, 256, 0, stream>>>(x, w_ih, b_h, outb, wsb);
  k_recur  <<<256, 512, 0, stream>>>(w_hh, outb, wsb);
  k_outproj<<<(NBATCH * NT) / 32, 256, 0, stream>>>(outb, wsb, w_out, b_out, outb);
}

// Round 15
// 5509.044 us; speedup vs baseline: 1.0039x; 1.0039x over previous
//
#include <hip/hip_runtime.h>

// RNN + FC readout on MI355X — f32 recurrence, quarter-split, 2-batch sub-step interleave.
//   A: xp[B,T,H] = input @ w_ih^T + b_h   (f32 GEMM; cols 0..255 -> d_out, 256..511 -> d_ws)
//   B: h_t = tanh(xp_t + h_{t-1} @ w_hh^T): 128 blocks = 32 groups x 4 quarters; each block
//      runs TWO batches (bA,bB) per tick with interleaved {spin|FMA|finalize|probe} so each
//      batch's publish->probe RTT flies under the OTHER batch's compute. Probes issued
//      ~1 tick before use (R10's serial-section failure: 0.05 ticks). 3 lgkm-barriers/tick.
//      W quarter all-register (128 f32/thread). Tagged u64 exchange (R11), pacc-LDS (R9).
//   C: out[B,T,O] = h @ w_out^T + b_out   (f16-dot2 GEMM, f32 in-place over d_out)
//
// Refuted: f16 W/h (R7), serial 2-batch sections (R10), wave-specialized barrier-free (R13),
// quad-DPP finalize + s_sleep pacing (R14: 8.4M bank conflicts). Proven: tagged u64 (R11),
// lgkm-only barriers (R12), pacc reduce + ownk-early FMA (R9/R12).

typedef _Float16 f16;
typedef __attribute__((ext_vector_type(2))) _Float16 half2_t;
typedef __attribute__((ext_vector_type(4))) float float4_t;

#define NIN    256
#define NHID   512
#define NOUT   256
#define NBATCH 64
#define NT     2048

#define FL4(p) (*reinterpret_cast<const float4_t*>(p))
#define LOADA(p)     __hip_atomic_load((p), __ATOMIC_RELAXED, __HIP_MEMORY_SCOPE_AGENT)
#define STOREA(p, v) __hip_atomic_store((p), (v), __ATOMIC_RELAXED, __HIP_MEMORY_SCOPE_AGENT)

// LDS-only barrier (R12-proven): orders ds ops without draining vmcnt.
#define LDS_BAR() do {                                              \
    asm volatile("s_waitcnt lgkmcnt(0)\n\ts_barrier" ::: "memory"); \
    __builtin_amdgcn_sched_barrier(0);                              \
  } while (0)

#if __has_builtin(__builtin_amdgcn_fdot2)
__device__ __forceinline__ float fdot2f(half2_t a, half2_t b, float c) {
  return __builtin_amdgcn_fdot2(a, b, c, false);   // v_dot2_f32_f16 (phase C only)
}
#else
__device__ __forceinline__ float fdot2f(half2_t a, half2_t b, float c) {
  return c + (float)a.x * (float)b.x + (float)a.y * (float)b.y;
}
#endif

__device__ __forceinline__ float tanh_fast(float x) {   // R5/R12-proven
  float e = __expf(2.0f * x);
  return 1.0f - 2.0f / (e + 1.0f);
}

__device__ unsigned long long g_pub[NBATCH][2][NHID];   // (tag s+1)<<32 | f32 bits; 512 KB

__global__ __launch_bounds__(256) void k_zero() {
  ((unsigned long long*)g_pub)[blockIdx.x * 256 + threadIdx.x] = 0ull;   // grid 256
}

// ---------------- Phase A: in-projection GEMM, full f32 (proven R5..R14) ----------------
__global__ __launch_bounds__(256) void k_inproj(
    const float* __restrict__ x, const float* __restrict__ w,
    const float* __restrict__ bias, float* __restrict__ xplo, float* __restrict__ xphi)
{
  __shared__ float xs[32][260];
  __shared__ float wsT[8][520];
  const int t = threadIdx.x;
  const int m0 = blockIdx.x * 32;
  const int mthr = t & 3;
  const int nthr = t >> 2;

  #pragma unroll
  for (int r = 0; r < 8; ++r) {
    int f = (t + 256 * r) * 4;
    int row = f >> 8, col = f & 255;
    *(float4_t*)&xs[row][col] =
        *reinterpret_cast<const float4_t*>(x + (size_t)(m0 + row) * NIN + col);
  }

  float acc[8][8];
  #pragma unroll
  for (int nn = 0; nn < 8; ++nn) {
    float bv = bias[nthr * 8 + nn];
    #pragma unroll
    for (int mm = 0; mm < 8; ++mm) acc[nn][mm] = bv;
  }

  for (int kc = 0; kc < 32; ++kc) {
    __syncthreads();
    #pragma unroll
    for (int r = 0; r < 4; ++r) {
      int f = (t + 256 * r) * 4;
      int n = f >> 3, k0 = f & 7;
      float4_t v = *reinterpret_cast<const float4_t*>(w + (size_t)n * NIN + kc * 8 + k0);
      #pragma unroll
      for (int j = 0; j < 4; ++j) wsT[k0 + j][n] = v[j];
    }
    __syncthreads();
    #pragma unroll
    for (int kp = 0; kp < 8; ++kp) {
      float4_t wv0 = *(const float4_t*)&wsT[kp][nthr * 8];
      float4_t wv1 = *(const float4_t*)&wsT[kp][nthr * 8 + 4];
      #pragma unroll
      for (int mm = 0; mm < 8; ++mm) {
        float xv = xs[mthr * 8 + mm][kc * 8 + kp];
        acc[0][mm] = fmaf(wv0.x, xv, acc[0][mm]);
        acc[1][mm] = fmaf(wv0.y, xv, acc[1][mm]);
        acc[2][mm] = fmaf(wv0.z, xv, acc[2][mm]);
        acc[3][mm] = fmaf(wv0.w, xv, acc[3][mm]);
        acc[4][mm] = fmaf(wv1.x, xv, acc[4][mm]);
        acc[5][mm] = fmaf(wv1.y, xv, acc[5][mm]);
        acc[6][mm] = fmaf(wv1.z, xv, acc[6][mm]);
        acc[7][mm] = fmaf(wv1.w, xv, acc[7][mm]);
      }
    }
  }

  const int n0 = nthr * 8;
  float* dst = (n0 < 256) ? (xplo + n0) : (xphi + (n0 - 256));
  #pragma unroll
  for (int mm = 0; mm < 8; ++mm) {
    int m = m0 + mthr * 8 + mm;
    float4_t o0 = {acc[0][mm], acc[1][mm], acc[2][mm], acc[3][mm]};
    float4_t o1 = {acc[4][mm], acc[5][mm], acc[6][mm], acc[7][mm]};
    *reinterpret_cast<float4_t*>(dst + (size_t)m * 256)     = o0;
    *reinterpret_cast<float4_t*>(dst + (size_t)m * 256 + 4) = o1;
  }
}

// ---------------- Phase B: f32 recurrence, 2-batch sub-step interleave ----------------
// block g in [0,128): xcd=g&7, q=(g>>3)&3, hi=g>>5; group G=xcd+8*hi in [0,32);
// batches bA=2G, bB=2G+1. thread t: js=t&63 -> rows r0=q*128+2js, r1; ks=t>>6 (wave)
// -> k-slice [ks*64,+64); ownk=(ks>>1==q); prow=(q*128+128+t)&511 (t<384).
// Tick (step s for both batches):
//  [ownk FMA_A][spinA->hlA] BAR1 [ownk FMA_B][!ownk FMA_A][spinB->hlB] BAR2
//  [finA+pubA+probeA][!ownk FMA_B] BAR3 [finB+pubB+probeB]
__global__ __launch_bounds__(512, 1) void k_recur(
    const float* __restrict__ whh, float* outbuf, float* wsbuf)
{
  __shared__ __align__(16) float hlA[2][NHID], hlB[2][NHID];
  __shared__ __align__(16) float paccA[8][128], paccB[8][128];
  const int g = blockIdx.x;
  const int q = (g >> 3) & 3;
  const int G = (g & 7) + 8 * (g >> 5);
  const int bA = 2 * G, bB = 2 * G + 1;
  const int t = threadIdx.x;
  const int js = t & 63;
  const int ks = t >> 6;
  const int r0 = q * 128 + js * 2, r1 = r0 + 1;
  const bool ownk = (ks >> 1) == q;
  const int prow = (q * 128 + 128 + t) & 511;       // partner row handled by t (t<384)

  float4_t w0[16], w1[16];
  #pragma unroll
  for (int i = 0; i < 16; ++i) {
    w0[i] = FL4(whh + (size_t)r0 * NHID + ks * 64 + i * 4);
    w1[i] = FL4(whh + (size_t)r1 * NHID + ks * 64 + i * 4);
  }

  float* xpA = nullptr;
  float* xpB = nullptr;
  float xqA0 = 0.f, xqA1 = 0.f, xqB0 = 0.f, xqB1 = 0.f;
  if (t < 128) {
    float* base = (q < 2) ? (outbuf + q * 128) : (wsbuf + (q - 2) * 128);
    xpA = base + (size_t)bA * NT * 256 + t;
    xpB = base + (size_t)bB * NT * 256 + t;
    xqA0 = xpA[0]; xqA1 = xpA[256];
    xqB0 = xpB[0]; xqB1 = xpB[256];
  }

  hlA[0][t] = 0.0f; hlB[0][t] = 0.0f;               // h_{-1} = 0
  __syncthreads();                                  // prologue: full drain once

  unsigned long long pvA = 0, pvB = 0;              // probes (issued at prev tick's fins)

  #define FMA_BODY(HL, PACC)                                                     \
  {                                                                              \
    const float4_t* h4 = (const float4_t*)&HL[par][ks * 64];                     \
    float4_t a0 = {0.f,0.f,0.f,0.f}, a1 = {0.f,0.f,0.f,0.f};                     \
    float4_t b0 = {0.f,0.f,0.f,0.f}, b1 = {0.f,0.f,0.f,0.f};                     \
    _Pragma("unroll")                                                            \
    for (int i = 0; i < 16; i += 2) {                                            \
      float4_t hA = h4[i], hB = h4[i + 1];                                       \
      a0 += w0[i] * hA;  a1 += w0[i + 1] * hB;                                   \
      b0 += w1[i] * hA;  b1 += w1[i + 1] * hB;                                   \
    }                                                                            \
    float4_t av = a0 + a1, bv = b0 + b1;                                         \
    PACC[ks][js * 2]     = (av.x + av.y) + (av.z + av.w);                        \
    PACC[ks][js * 2 + 1] = (bv.x + bv.y) + (bv.z + bv.w);                        \
  }

  #define FIN_BODY(BB, HL, PACC, XP, XQ0, XQ1, PV)                               \
  {                                                                              \
    if (t < 128) {                                                               \
      float sum = PACC[0][t];                                                    \
      _Pragma("unroll")                                                          \
      for (int k2 = 1; k2 < 8; ++k2) sum += PACC[k2][t];                         \
      float h = tanh_fast(sum + XQ0);                                            \
      STOREA(&g_pub[BB][par][q * 128 + t],                                       \
             ((unsigned long long)(unsigned)(s + 1) << 32) |                     \
             (unsigned long long)__builtin_bit_cast(unsigned, h));               \
      HL[par ^ 1][q * 128 + t] = h;                                              \
      XP[(size_t)s * 256] = h;                                                   \
      XQ0 = XQ1;                                                                 \
      if (s + 2 < NT) XQ1 = XP[(size_t)(s + 2) * 256];                           \
    }                                                                            \
    if (s + 1 < NT && t < 384)                                                   \
      PV = LOADA(&g_pub[BB][(s + 1) & 1 ^ 1][prow]);  /* slot s&1 for h(s) */    \
  }

  for (int s = 0; s < NT; ++s) {
    const int par = s & 1;

    if (ownk) FMA_BODY(hlA, paccA);                 // own rows ready since last finA
    if (s > 0 && t < 384) {                         // spin A (probe issued last tick)
      while ((unsigned)(pvA >> 32) < (unsigned)s)
        pvA = LOADA(&g_pub[bA][(s - 1) & 1][prow]);
      hlA[par][prow] = __builtin_bit_cast(float, (unsigned)pvA);
    }
    LDS_BAR();                                      // BAR1: hlA[par] complete

    if (ownk) FMA_BODY(hlB, paccB);                 // hlB own rows: last finB + BAR1
    if (!ownk) FMA_BODY(hlA, paccA);
    if (s > 0 && t < 384) {                         // spin B
      while ((unsigned)(pvB >> 32) < (unsigned)s)
        pvB = LOADA(&g_pub[bB][(s - 1) & 1][prow]);
      hlB[par][prow] = __builtin_bit_cast(float, (unsigned)pvB);
    }
    LDS_BAR();                                      // BAR2: paccA + hlB[par] complete

    FIN_BODY(bA, hlA, paccA, xpA, xqA0, xqA1, pvA)  // publish A; probe A (~0.6 tick early)
    if (!ownk) FMA_BODY(hlB, paccB);
    LDS_BAR();                                      // BAR3: paccB complete

    FIN_BODY(bB, hlB, paccB, xpB, xqB0, xqB1, pvB)  // publish B; probe B (~1 tick early)
  }
  #undef FMA_BODY
  #undef FIN_BODY
}

// ---------------- Phase C: out-projection (f16 dot2, f32 out, in-place; proven) ------------
__global__ __launch_bounds__(256) void k_outproj(
    const float* hlo, const float* hhi, const float* __restrict__ w,
    const float* __restrict__ bias, float* out)
{
  __shared__ half2_t xs[32][258];
  __shared__ half2_t ws[256][19];
  const int t = threadIdx.x;
  const int m0 = blockIdx.x * 32;
  const int nthr = t >> 2;
  const int mthr = t & 3;

  #pragma unroll
  for (int r = 0; r < 16; ++r) {
    int f = (t + 256 * r) * 4;
    int row = f >> 9, col = f & 511;
    const float* src = (col < 256) ? (hlo + (size_t)(m0 + row) * 256 + col)
                                   : (hhi + (size_t)(m0 + row) * 256 + (col - 256));
    float4_t v = *reinterpret_cast<const float4_t*>(src);
    xs[row][(col >> 1)]     = half2_t{(f16)v.x, (f16)v.y};
    xs[row][(col >> 1) + 1] = half2_t{(f16)v.z, (f16)v.w};
  }

  float acc[4][8];
  #pragma unroll
  for (int nn = 0; nn < 4; ++nn) {
    float bv = bias[nthr * 4 + nn];
    #pragma unroll
    for (int mm = 0; mm < 8; ++mm) acc[nn][mm] = bv;
  }

  for (int kc = 0; kc < 16; ++kc) {
    __syncthreads();
    #pragma unroll
    for (int r = 0; r < 8; ++r) {
      int f = (t + 256 * r) * 4;
      int row = f >> 5, col = f & 31;
      float4_t v = *reinterpret_cast<const float4_t*>(w + (size_t)row * NHID + kc * 32 + col);
      ws[row][(col >> 1)]     = half2_t{(f16)v.x, (f16)v.y};
      ws[row][(col >> 1) + 1] = half2_t{(f16)v.z, (f16)v.w};
    }
    __syncthreads();
    #pragma unroll
    for (int kp = 0; kp < 16; ++kp) {
      half2_t wv[4], xv[8];
      #pragma unroll
      for (int nn = 0; nn < 4; ++nn) wv[nn] = ws[nthr * 4 + nn][kp];
      #pragma unroll
      for (int mm = 0; mm < 8; ++mm) xv[mm] = xs[mthr * 8 + mm][kc * 16 + kp];
      #pragma unroll
      for (int nn = 0; nn < 4; ++nn)
        #pragma unroll
        for (int mm = 0; mm < 8; ++mm)
          acc[nn][mm] = fdot2f(wv[nn], xv[mm], acc[nn][mm]);
    }
  }

  #pragma unroll
  for (int mm = 0; mm < 8; ++mm) {
    int m = m0 + mthr * 8 + mm;
    float4_t o = {acc[0][mm], acc[1][mm], acc[2][mm], acc[3][mm]};
    *reinterpret_cast<float4_t*>(out + (size_t)m * NOUT + nthr * 4) = o;
  }
}

extern "C" void kernel_launch(void* const* d_in, const int* in_sizes, int n_in,
                              void* d_out, int out_size, void* d_ws, size_t ws_size,
                              hipStream_t stream) {
  (void)in_sizes; (void)n_in; (void)ws_size; (void)out_size;
  const float* x     = (const float*)d_in[0];
  const float* w_ih  = (const float*)d_in[1];
  const float* w_hh  = (const float*)d_in[2];
  const float* b_h   = (const float*)d_in[3];
  const float* w_out = (const float*)d_in[4];
  const float* b_out = (const float*)d_in[5];

  float* outb = (float*)d_out;   // xp cols 0..255  -> h rows 0..255  -> y   (134 MB)
  float* wsb  = (float*)d_ws;    // xp cols 256..511 -> h rows 256..511     (134 MB, proven)

  k_zero   <<<256, 256, 0, stream>>>();
  k_inproj <<<(NBATCH * NT) / 32, 256, 0, stream>>>(x, w_ih, b_h, outb, wsb);
  k_recur  <<<128, 512, 0, stream>>>(w_hh, outb, wsb);
  k_outproj<<<(NBATCH * NT) / 32, 256, 0, stream>>>(outb, wsb, w_out, b_out, outb);
}

// Round 16
// 3762.045 us; speedup vs baseline: 1.4701x; 1.4644x over previous
//
#include <hip/hip_runtime.h>

// RNN + FC readout on MI355X — R12 champion + L2-peek probe (same-XCD fast path).
//   A: xp[B,T,H] = input @ w_ih^T + b_h   (f32 GEMM; cols 0..255 -> d_out, 256..511 -> d_ws)
//   B: h_t = tanh(xp_t + h_{t-1} @ w_hh^T): 256 blocks = 4/batch; W quarter all-register.
//      Tagged u64 exchange (R11). lgkm-only barriers (R12). Spin retries ALTERNATE between
//      sc0-only global_load (served by the XCD-shared L2 — peers share g&7 -> same XCD under
//      round-robin; publisher's agent store writes THROUGH that L2) and the LLC atomic load
//      (guarantees progress if the same-XCD/write-through assumption fails; tag validates
//      every read, so this is unconditionally correct and hang-free).
//   C: out[B,T,O] = h @ w_out^T + b_out   (f16-dot2 GEMM, f32 in-place over d_out)
//
// Refuted: f16 W/h (R7), serial 2-batch (R10), wave-specialized (R13), quad-DPP+s_sleep
// (R14), sub-step 2-batch interleave (R15: 4.78ms, half-chip). Champion basis: R12 3.07ms.

typedef _Float16 f16;
typedef __attribute__((ext_vector_type(2))) _Float16 half2_t;
typedef __attribute__((ext_vector_type(4))) float float4_t;

#define NIN    256
#define NHID   512
#define NOUT   256
#define NBATCH 64
#define NT     2048

#define FL4(p) (*reinterpret_cast<const float4_t*>(p))
#define LOADA(p)     __hip_atomic_load((p), __ATOMIC_RELAXED, __HIP_MEMORY_SCOPE_AGENT)
#define STOREA(p, v) __hip_atomic_store((p), (v), __ATOMIC_RELAXED, __HIP_MEMORY_SCOPE_AGENT)

// LDS-only barrier (R12-proven): orders ds ops without draining vmcnt.
#define LDS_BAR() do {                                              \
    asm volatile("s_waitcnt lgkmcnt(0)\n\ts_barrier" ::: "memory"); \
    __builtin_amdgcn_sched_barrier(0);                              \
  } while (0)

// sc0-only 8B load: bypass L0/L1, serviced at the XCD-shared L2 (NOT forced to LLC).
// Publisher's agent store passes through the same physical L2 when peers share the XCD,
// so this observes fresh data at ~L2 latency. Tag-validated by caller; never trusted blind.
__device__ __forceinline__ unsigned long long l2_peek(const unsigned long long* p) {
  unsigned long long v;
  asm volatile("global_load_dwordx2 %0, %1, off sc0\n\t"
               "s_waitcnt vmcnt(0)"
               : "=v"(v) : "v"(p) : "memory");
  return v;
}

#if __has_builtin(__builtin_amdgcn_fdot2)
__device__ __forceinline__ float fdot2f(half2_t a, half2_t b, float c) {
  return __builtin_amdgcn_fdot2(a, b, c, false);   // v_dot2_f32_f16 (phase C only)
}
#else
__device__ __forceinline__ float fdot2f(half2_t a, half2_t b, float c) {
  return c + (float)a.x * (float)b.x + (float)a.y * (float)b.y;
}
#endif

__device__ __forceinline__ float tanh_fast(float x) {   // R5/R12-proven
  float e = __expf(2.0f * x);
  return 1.0f - 2.0f / (e + 1.0f);
}

__device__ unsigned long long g_pub[NBATCH][2][NHID];   // (tag s+1)<<32 | f32 bits; 512 KB

__global__ __launch_bounds__(256) void k_zero() {
  ((unsigned long long*)g_pub)[blockIdx.x * 256 + threadIdx.x] = 0ull;   // grid 256
}

// ---------------- Phase A: in-projection GEMM, full f32 (proven R5..R15) ----------------
__global__ __launch_bounds__(256) void k_inproj(
    const float* __restrict__ x, const float* __restrict__ w,
    const float* __restrict__ bias, float* __restrict__ xplo, float* __restrict__ xphi)
{
  __shared__ float xs[32][260];
  __shared__ float wsT[8][520];
  const int t = threadIdx.x;
  const int m0 = blockIdx.x * 32;
  const int mthr = t & 3;
  const int nthr = t >> 2;

  #pragma unroll
  for (int r = 0; r < 8; ++r) {
    int f = (t + 256 * r) * 4;
    int row = f >> 8, col = f & 255;
    *(float4_t*)&xs[row][col] =
        *reinterpret_cast<const float4_t*>(x + (size_t)(m0 + row) * NIN + col);
  }

  float acc[8][8];
  #pragma unroll
  for (int nn = 0; nn < 8; ++nn) {
    float bv = bias[nthr * 8 + nn];
    #pragma unroll
    for (int mm = 0; mm < 8; ++mm) acc[nn][mm] = bv;
  }

  for (int kc = 0; kc < 32; ++kc) {
    __syncthreads();
    #pragma unroll
    for (int r = 0; r < 4; ++r) {
      int f = (t + 256 * r) * 4;
      int n = f >> 3, k0 = f & 7;
      float4_t v = *reinterpret_cast<const float4_t*>(w + (size_t)n * NIN + kc * 8 + k0);
      #pragma unroll
      for (int j = 0; j < 4; ++j) wsT[k0 + j][n] = v[j];
    }
    __syncthreads();
    #pragma unroll
    for (int kp = 0; kp < 8; ++kp) {
      float4_t wv0 = *(const float4_t*)&wsT[kp][nthr * 8];
      float4_t wv1 = *(const float4_t*)&wsT[kp][nthr * 8 + 4];
      #pragma unroll
      for (int mm = 0; mm < 8; ++mm) {
        float xv = xs[mthr * 8 + mm][kc * 8 + kp];
        acc[0][mm] = fmaf(wv0.x, xv, acc[0][mm]);
        acc[1][mm] = fmaf(wv0.y, xv, acc[1][mm]);
        acc[2][mm] = fmaf(wv0.z, xv, acc[2][mm]);
        acc[3][mm] = fmaf(wv0.w, xv, acc[3][mm]);
        acc[4][mm] = fmaf(wv1.x, xv, acc[4][mm]);
        acc[5][mm] = fmaf(wv1.y, xv, acc[5][mm]);
        acc[6][mm] = fmaf(wv1.z, xv, acc[6][mm]);
        acc[7][mm] = fmaf(wv1.w, xv, acc[7][mm]);
      }
    }
  }

  const int n0 = nthr * 8;
  float* dst = (n0 < 256) ? (xplo + n0) : (xphi + (n0 - 256));
  #pragma unroll
  for (int mm = 0; mm < 8; ++mm) {
    int m = m0 + mthr * 8 + mm;
    float4_t o0 = {acc[0][mm], acc[1][mm], acc[2][mm], acc[3][mm]};
    float4_t o1 = {acc[4][mm], acc[5][mm], acc[6][mm], acc[7][mm]};
    *reinterpret_cast<float4_t*>(dst + (size_t)m * 256)     = o0;
    *reinterpret_cast<float4_t*>(dst + (size_t)m * 256 + 4) = o1;
  }
}

// ---------------- Phase B: f32 recurrence, quarter-split, L2-peek tagged exchange ----------
// block g: batch b=(g>>5)*8+(g&7), quarter q=(g>>3)&3 owns rows [q*128,+128).
// thread t: js=t&63 -> rows r0=q*128+js*2, r1; ks=t>>6 (wave) -> k-slice [ks*64,+64).
// W: w0[16],w1[16] float4 = 128 regs. pacc-LDS reduction. 3 lgkm barriers/step (R12).
__global__ __launch_bounds__(512, 1) void k_recur(
    const float* __restrict__ whh, float* outbuf, float* wsbuf)
{
  __shared__ __align__(16) float hb[2][NHID];
  __shared__ __align__(16) float pacc[8][128];
  const int g = blockIdx.x;
  const int b = (g >> 5) * 8 + (g & 7);
  const int q = (g >> 3) & 3;
  const int t = threadIdx.x;
  const int js = t & 63;
  const int ks = t >> 6;
  const int r0 = q * 128 + js * 2, r1 = r0 + 1;
  const bool ownk = (ks >> 1) == q;
  const int prow = (q * 128 + 128 + t) & 511;       // partner row handled by t (t<384)

  float4_t w0[16], w1[16];
  #pragma unroll
  for (int i = 0; i < 16; ++i) {
    w0[i] = FL4(whh + (size_t)r0 * NHID + ks * 64 + i * 4);
    w1[i] = FL4(whh + (size_t)r1 * NHID + ks * 64 + i * 4);
  }

  float* xp = ((q < 2) ? (outbuf + q * 128) : (wsbuf + (q - 2) * 128))
              + (size_t)b * NT * 256 + t;           // used by t<128 only
  float xq0 = 0.f, xq1 = 0.f;
  if (t < 128) { xq0 = xp[0]; xq1 = xp[256]; }

  hb[0][t] = 0.0f;                                  // h_{-1} = 0
  __syncthreads();                                  // prologue: full drain once

  for (int s = 0; s < NT; ++s) {
    float* hbc = hb[s & 1];
    float* hbn = hb[(s & 1) ^ 1];

    // speculative probe (LLC atomic; compiler defers the waitcnt to first use -> overlaps FMA)
    const bool rd = (s > 0) && (t < 384);
    const unsigned long long* paddr = &g_pub[b][(s - 1) & 1][prow];
    unsigned long long pv = 0;
    if (rd) pv = LOADA(paddr);

    float4_t a0 = {0.f,0.f,0.f,0.f}, a1 = {0.f,0.f,0.f,0.f};
    float4_t b0 = {0.f,0.f,0.f,0.f}, b1 = {0.f,0.f,0.f,0.f};
    if (ownk) {                                     // overlaps the probe's flight
      const float4_t* h4 = (const float4_t*)&hbc[ks * 64];
      #pragma unroll
      for (int i = 0; i < 16; i += 2) {
        float4_t hA = h4[i], hB = h4[i + 1];
        a0 += w0[i] * hA;  a1 += w0[i + 1] * hB;
        b0 += w1[i] * hA;  b1 += w1[i + 1] * hB;
      }
    }

    if (rd) {                                       // spin: alternate L2 peek / LLC atomic
      int it = 0;
      while ((unsigned)(pv >> 32) < (unsigned)s)
        pv = (++it & 1) ? l2_peek(paddr) : LOADA(paddr);
      hbc[prow] = __builtin_bit_cast(float, (unsigned)pv);
    }
    LDS_BAR();                                      // full h_{s-1} in hbc (ds-order only)

    if (!ownk) {                                    // partner-k (zeros at s==0: correct)
      const float4_t* h4 = (const float4_t*)&hbc[ks * 64];
      #pragma unroll
      for (int i = 0; i < 16; i += 2) {
        float4_t hA = h4[i], hB = h4[i + 1];
        a0 += w0[i] * hA;  a1 += w0[i + 1] * hB;
        b0 += w1[i] * hA;  b1 += w1[i + 1] * hB;
      }
    }

    float4_t av = a0 + a1, bv = b0 + b1;
    pacc[ks][js * 2]     = (av.x + av.y) + (av.z + av.w);
    pacc[ks][js * 2 + 1] = (bv.x + bv.y) + (bv.z + bv.w);
    LDS_BAR();                                      // pacc complete

    if (t < 128) {                                  // finalize row q*128+t
      float sum = pacc[0][t];
      #pragma unroll
      for (int k2 = 1; k2 < 8; ++k2) sum += pacc[k2][t];
      float h = tanh_fast(sum + xq0);
      STOREA(&g_pub[b][s & 1][q * 128 + t],         // publish first: peers see ASAP
             ((unsigned long long)(unsigned)(s + 1) << 32) |
             (unsigned long long)__builtin_bit_cast(unsigned, h));
      hbn[q * 128 + t] = h;                         // own rows for next step
      xp[(size_t)s * 256] = h;                      // hs for phase C (fire-and-forget)
      xq0 = xq1;
      if (s + 2 < NT) xq1 = xp[(size_t)(s + 2) * 256];   // 2-step HBM prefetch
    }
    LDS_BAR();                                      // hbn ready (ds-order only)
  }
}

// ---------------- Phase C: out-projection (f16 dot2, f32 out, in-place; proven) ------------
__global__ __launch_bounds__(256) void k_outproj(
    const float* hlo, const float* hhi, const float* __restrict__ w,
    const float* __restrict__ bias, float* out)
{
  __shared__ half2_t xs[32][258];
  __shared__ half2_t ws[256][19];
  const int t = threadIdx.x;
  const int m0 = blockIdx.x * 32;
  const int nthr = t >> 2;
  const int mthr = t & 3;

  #pragma unroll
  for (int r = 0; r < 16; ++r) {
    int f = (t + 256 * r) * 4;
    int row = f >> 9, col = f & 511;
    const float* src = (col < 256) ? (hlo + (size_t)(m0 + row) * 256 + col)
                                   : (hhi + (size_t)(m0 + row) * 256 + (col - 256));
    float4_t v = *reinterpret_cast<const float4_t*>(src);
    xs[row][(col >> 1)]     = half2_t{(f16)v.x, (f16)v.y};
    xs[row][(col >> 1) + 1] = half2_t{(f16)v.z, (f16)v.w};
  }

  float acc[4][8];
  #pragma unroll
  for (int nn = 0; nn < 4; ++nn) {
    float bv = bias[nthr * 4 + nn];
    #pragma unroll
    for (int mm = 0; mm < 8; ++mm) acc[nn][mm] = bv;
  }

  for (int kc = 0; kc < 16; ++kc) {
    __syncthreads();
    #pragma unroll
    for (int r = 0; r < 8; ++r) {
      int f = (t + 256 * r) * 4;
      int row = f >> 5, col = f & 31;
      float4_t v = *reinterpret_cast<const float4_t*>(w + (size_t)row * NHID + kc * 32 + col);
      ws[row][(col >> 1)]     = half2_t{(f16)v.x, (f16)v.y};
      ws[row][(col >> 1) + 1] = half2_t{(f16)v.z, (f16)v.w};
    }
    __syncthreads();
    #pragma unroll
    for (int kp = 0; kp < 16; ++kp) {
      half2_t wv[4], xv[8];
      #pragma unroll
      for (int nn = 0; nn < 4; ++nn) wv[nn] = ws[nthr * 4 + nn][kp];
      #pragma unroll
      for (int mm = 0; mm < 8; ++mm) xv[mm] = xs[mthr * 8 + mm][kc * 16 + kp];
      #pragma unroll
      for (int nn = 0; nn < 4; ++nn)
        #pragma unroll
        for (int mm = 0; mm < 8; ++mm)
          acc[nn][mm] = fdot2f(wv[nn], xv[mm], acc[nn][mm]);
    }
  }

  #pragma unroll
  for (int mm = 0; mm < 8; ++mm) {
    int m = m0 + mthr * 8 + mm;
    float4_t o = {acc[0][mm], acc[1][mm], acc[2][mm], acc[3][mm]};
    *reinterpret_cast<float4_t*>(out + (size_t)m * NOUT + nthr * 4) = o;
  }
}

extern "C" void kernel_launch(void* const* d_in, const int* in_sizes, int n_in,
                              void* d_out, int out_size, void* d_ws, size_t ws_size,
                              hipStream_t stream) {
  (void)in_sizes; (void)n_in; (void)ws_size; (void)out_size;
  const float* x     = (const float*)d_in[0];
  const float* w_ih  = (const float*)d_in[1];
  const float* w_hh  = (const float*)d_in[2];
  const float* b_h   = (const float*)d_in[3];
  const float* w_out = (const float*)d_in[4];
  const float* b_out = (const float*)d_in[5];

  float* outb = (float*)d_out;   // xp cols 0..255  -> h rows 0..255  -> y   (134 MB)
  float* wsb  = (float*)d_ws;    // xp cols 256..511 -> h rows 256..511     (134 MB, proven)

  k_zero   <<<256, 256, 0, stream>>>();
  k_inproj <<<(NBATCH * NT) / 32, 256, 0, stream>>>(x, w_ih, b_h, outb, wsb);
  k_recur  <<<256, 512, 0, stream>>>(w_hh, outb, wsb);
  k_outproj<<<(NBATCH * NT) / 32, 256, 0, stream>>>(outb, wsb, w_out, b_out, outb);
}